// Round 15
// baseline (265.641 us; speedup 1.0000x reference)
//
#include <hip/hip_runtime.h>

#define N_NODES 50000
#define N_EDGES 800000
#define F_IN 128
#define HIDDEN 128
#define N_CLASSES 40

#define NBUCKET 391      // buckets of 128 nodes (dst>>7); 391*128 = 50048
#define BUCKET_CAP 4096  // per-bucket capacity (mean fill 2048, sd ~45)
#define BINA_CHUNK 2048
#define BINA_NBLK 391    // ceil(800000/2048)
#define PREP_ITEMS (N_NODES * 32 + 128 * 256 + 80 * 128)  // 1,643,008
#define PREP_NBLK (PREP_ITEMS / 256)                       // 6418 (exact)

// workspace element offsets (4B units)
// Overlay audit (R10 lesson): xb LIVE through k_fused; bins dead after
// k_binB; pb/q overlay dead bins only; nothing overlays live xb.
// xb is CHUNK-MAJOR: ushort[4][N][32] — each 3.2 MB chunk fits one XCD L2.
#define OFF_RS     0          // int[N+1]
#define OFF_BCNT   50004      // int[391] global bucket counts
#define OFF_INVDEG 100004     // float[N]
#define OFF_SRCS   150004     // int[E] -> ends 950,004
#define OFF_XB     950004     // ushort[4][N][32] bf16 x -> ends 4,150,004; LIVE through k_fused
#define OFF_BINS   7350004    // int[391*4096] -> ends 8,951,540; dead after k_binB
#define OFF_PB     7350004    // ushort[N*40] bf16 p (overlays dead bins) -> ends 8,350,004
#define OFF_Q      8350004    // float[N*40] (overlays dead bins tail) -> ends 10,350,004
#define OFF_WT1    10550004   // ushort[128*256] -> ends 10,566,388
#define OFF_WT2    10566388   // ushort[80*128]  -> ends 10,571,508
// total 10,571,508 float-units = 42.3 MB (proven available)

typedef short bf16x8 __attribute__((ext_vector_type(8)));
typedef float f32x4 __attribute__((ext_vector_type(4)));
typedef unsigned short u16x8 __attribute__((ext_vector_type(8)));

static __device__ __forceinline__ unsigned short f2bf(float f) {
  unsigned int u = __builtin_bit_cast(unsigned int, f);
  u = (u + 0x7fffu + ((u >> 16) & 1u)) >> 16;  // RNE; inputs are finite
  return (unsigned short)u;
}
static __device__ __forceinline__ float bf2f(unsigned short s) {
  unsigned int u = ((unsigned int)s) << 16;
  return __builtin_bit_cast(float, u);
}

// ---------------------------------------------------------------------------
// Fused: bucket-sort phase A (blocks 0..390) + weight/x prep (blocks 391+).
__global__ __launch_bounds__(256) void k_binA_prep(
    const int* __restrict__ src, const int* __restrict__ dst,
    int* __restrict__ bcnt, int* __restrict__ bins,
    const float* __restrict__ x, const float* __restrict__ W1l,
    const float* __restrict__ W1r, const float* __restrict__ W2l,
    const float* __restrict__ W2r, unsigned short* __restrict__ xb,
    unsigned short* __restrict__ Wt1, unsigned short* __restrict__ Wt2) {
  if (blockIdx.x >= BINA_NBLK) {
    // ---- prep path (independent of CSR build) ----
    int idx = (blockIdx.x - BINA_NBLK) * 256 + threadIdx.x;
    if (idx < N_NODES * 32) {  // x fp32 -> bf16, chunk-major layout
      int row = idx >> 5, c4 = (idx & 31) << 2;  // elem offset 0..124
      const float4 v = *(const float4*)(x + (size_t)row * F_IN + c4);
      ushort4 o;
      o.x = f2bf(v.x); o.y = f2bf(v.y); o.z = f2bf(v.z); o.w = f2bf(v.w);
      int cc = c4 >> 5, wi = c4 & 31;
      *(ushort4*)(xb + ((size_t)cc * N_NODES + row) * 32 + wi) = o;
      return;
    }
    idx -= N_NODES * 32;
    if (idx < 128 * 256) {
      int n = idx >> 8, k = idx & 255;
      float v = (k < 128) ? W1l[(size_t)k * 128 + n]
                          : W1r[(size_t)(k - 128) * 128 + n];
      Wt1[(size_t)n * 256 + k] = f2bf(v);
    } else if (idx < 128 * 256 + 80 * 128) {
      int j = idx - 128 * 256;
      int n = j >> 7, k = j & 127;
      float v = (n < 40) ? W2l[(size_t)k * 40 + n]
                         : W2r[(size_t)k * 40 + (n - 40)];
      Wt2[(size_t)n * 128 + k] = f2bf(v);
    }
    return;
  }
  // ---- binA path: LDS counting sort of 2048 edges into 391 dst-buckets ----
  __shared__ int cnt[NBUCKET];
  __shared__ int excl[NBUCKET];
  __shared__ int cursor[NBUCKET];
  __shared__ int bbase[NBUCKET];
  __shared__ int sc[256];
  __shared__ int stage[BINA_CHUNK];
  __shared__ unsigned short bkt[BINA_CHUNK];
  int t = threadIdx.x;
  int e0 = blockIdx.x * BINA_CHUNK;
  int ne = N_EDGES - e0;
  if (ne > BINA_CHUNK) ne = BINA_CHUNK;
  for (int i = t; i < NBUCKET; i += 256) cnt[i] = 0;
  __syncthreads();
  for (int i = t; i < ne; i += 256) atomicAdd(&cnt[dst[e0 + i] >> 7], 1);
  __syncthreads();
  // exclusive scan over 391 with 256 threads: pair-sum then Hillis
  int a = (2 * t < NBUCKET) ? cnt[2 * t] : 0;
  int b2_ = (2 * t + 1 < NBUCKET) ? cnt[2 * t + 1] : 0;
  int s = a + b2_;
  sc[t] = s;
  __syncthreads();
  for (int off = 1; off < 256; off <<= 1) {
    int add = (t >= off) ? sc[t - off] : 0;
    __syncthreads();
    sc[t] += add;
    __syncthreads();
  }
  int pbase = sc[t] - s;  // exclusive prefix of my pair
  if (2 * t < NBUCKET) { excl[2 * t] = pbase; cursor[2 * t] = pbase; }
  if (2 * t + 1 < NBUCKET) {
    excl[2 * t + 1] = pbase + a;
    cursor[2 * t + 1] = pbase + a;
  }
  for (int i = t; i < NBUCKET; i += 256)
    bbase[i] = atomicAdd(&bcnt[i], cnt[i]);  // claim contiguous global range
  __syncthreads();
  for (int i = t; i < ne; i += 256) {
    int d = dst[e0 + i];
    int sv = src[e0 + i];
    int b = d >> 7;
    int pos = atomicAdd(&cursor[b], 1);
    stage[pos] = ((d & 127) << 16) | sv;  // src < 65536 fits 16 bits
    bkt[pos] = (unsigned short)b;
  }
  __syncthreads();
  for (int i = t; i < ne; i += 256) {
    int b = bkt[i];
    bins[(size_t)b * BUCKET_CAP + bbase[b] + (i - excl[b])] = stage[i];
  }
}

// ---------------------------------------------------------------------------
// Bucket-sort phase B: one block per bucket (128 nodes). Builds final CSR.
__global__ __launch_bounds__(256) void k_binB(
    const int* __restrict__ bcnt, const int* __restrict__ bins,
    int* __restrict__ rs, int* __restrict__ srcs,
    float* __restrict__ invdeg) {
  __shared__ int sc[256];
  __shared__ int hist[128];
  __shared__ int cursor[128];
  int b = blockIdx.x;
  int t = threadIdx.x;
  // base = sum(bcnt[0..b-1]); each thread covers t and t+256
  int v = 0;
  if (t < b) v += bcnt[t];
  if (t + 256 < b) v += bcnt[t + 256];
  sc[t] = v;
  __syncthreads();
  for (int off = 128; off; off >>= 1) {
    if (t < off) sc[t] += sc[t + off];
    __syncthreads();
  }
  int base = sc[0];
  int cnt = bcnt[b];
  const int* bb = bins + (size_t)b * BUCKET_CAP;
  if (t < 128) hist[t] = 0;
  __syncthreads();
  for (int i = t; i < cnt; i += 256) atomicAdd(&hist[bb[i] >> 16], 1);
  __syncthreads();
  int c = (t < 128) ? hist[t] : 0;
  sc[t] = c;
  __syncthreads();
  for (int off = 1; off < 128; off <<= 1) {
    int add = (t >= off) ? sc[t - off] : 0;
    __syncthreads();
    sc[t] += add;
    __syncthreads();
  }
  int lexcl = sc[t] - c;
  int node = b * 128 + t;
  if (t < 128 && node < N_NODES) {
    rs[node] = base + lexcl;
    invdeg[node] = 1.0f / (float)(c > 1 ? c : 1);
  }
  if (b == 0 && t == 0) rs[N_NODES] = N_EDGES;
  if (t < 128) cursor[t] = lexcl;
  __syncthreads();
  for (int i = t; i < cnt; i += 256) {
    int v2 = bb[i];
    int pos = atomicAdd(&cursor[v2 >> 16], 1);
    srcs[base + pos] = v2 & 0xFFFF;
  }
}

// ---------------------------------------------------------------------------
// FUSED gather + 2-layer MLP. Block = 64 rows, 8 waves (512 threads).
// Gather is FEATURE-CHUNKED: outer loop over 4 chunks of 32 dims; each
// chunk's xbc slice is 3.2 MB (< 4 MiB XCD L2) so random row reads become
// L2 hits after compulsory fill (R14: whole-row gather forced every XCD to
// pull all 12.8 MB of xb through its L2 = 110 MB L3 traffic).
// Lanes: 16 edge-slots x 4 lanes x 16B = 64 B/edge/chunk.
// h ALIASES into as after phase-1 (33 KB LDS total).
__global__ __launch_bounds__(512) void k_fused(
    const unsigned short* __restrict__ xb, const int* __restrict__ rs,
    const int* __restrict__ srcs, const float* __restrict__ invdeg,
    const unsigned short* __restrict__ Wt1, const unsigned short* __restrict__ Wt2,
    const float* __restrict__ b1, const float* __restrict__ b2,
    unsigned short* __restrict__ pb, float* __restrict__ q) {
  __shared__ unsigned short as[64 * 264];  // 33.0 KB; A=[agg|x], then h alias
  unsigned short* hs = as;                 // h: 64 x 132 = 16.9 KB, fits
  int w = threadIdx.x >> 6, lane = threadIdx.x & 63;
  int t = threadIdx.x;
  int row0 = blockIdx.x * 64;

  // ---- stage own-row x-half into as[., 128:256] (coalesced) ----
  for (int chunk = t; chunk < 64 * 16; chunk += 512) {  // 16 x 16B per row
    int lrow = chunk >> 4, p = chunk & 15;
    int cc = p >> 2, wi = (p & 3) * 8;
    int grow = row0 + lrow;
    if (grow >= N_NODES) grow = N_NODES - 1;
    u16x8 v = *(const u16x8*)(xb + ((size_t)cc * N_NODES + grow) * 32 + wi);
    *(u16x8*)(as + lrow * 264 + 128 + cc * 32 + wi) = v;  // = 128 + p*8
  }

  // ---- gather agg, chunk-major: 16 slots x 4 lanes, unrolled x2 ----
  int slot = lane >> 2, li = lane & 3;
  for (int cc = 0; cc < 4; cc++) {
    const unsigned short* xc = xb + (size_t)cc * N_NODES * 32;
    for (int j = 0; j < 8; j++) {
      int lrow = w * 8 + j;
      int node = row0 + lrow;
      int beg = 0, end = 0;
      if (node < N_NODES) { beg = rs[node]; end = rs[node + 1]; }
      float acc[8];
#pragma unroll
      for (int k = 0; k < 8; k++) acc[k] = 0.f;
      int i = beg + slot;
      for (; i + 16 < end; i += 32) {  // two edges per slot per iter
        int s0 = srcs[i], s1 = srcs[i + 16];
        u16x8 a0 = *(const u16x8*)(xc + (size_t)s0 * 32 + li * 8);
        u16x8 c0 = *(const u16x8*)(xc + (size_t)s1 * 32 + li * 8);
#pragma unroll
        for (int k = 0; k < 8; k++) acc[k] += bf2f(a0[k]) + bf2f(c0[k]);
      }
      if (i < end) {  // tail edge
        int s0 = srcs[i];
        u16x8 a0 = *(const u16x8*)(xc + (size_t)s0 * 32 + li * 8);
#pragma unroll
        for (int k = 0; k < 8; k++) acc[k] += bf2f(a0[k]);
      }
      // reduce across 16 slots (lane bits 2..5)
#pragma unroll
      for (int off = 4; off <= 32; off <<= 1)
#pragma unroll
        for (int k = 0; k < 8; k++) acc[k] += __shfl_xor(acc[k], off, 64);
      if (slot == 0) {  // lanes 0..3 hold dims cc*32 + li*8 .. +7
        int nidx = (node < N_NODES) ? node : 0;
        float inv = invdeg[nidx];
        u16x8 o;
#pragma unroll
        for (int k = 0; k < 8; k++) o[k] = f2bf(acc[k] * inv);
        *(u16x8*)(as + lrow * 264 + cc * 32 + li * 8) = o;
      }
    }
  }
  __syncthreads();

  // ---- phase 1: h = relu(A @ Wt1 + b1); wave w = n-tile w, 4 row-tiles ----
  int r = lane & 15, quad = lane >> 4;
  const unsigned short* Bp = Wt1 + (size_t)(w * 16 + r) * 256 + quad * 8;
  f32x4 acc1[4];
#pragma unroll
  for (int rt = 0; rt < 4; rt++) acc1[rt] = (f32x4){0.f, 0.f, 0.f, 0.f};
#pragma unroll
  for (int k0 = 0; k0 < 256; k0 += 32) {
    bf16x8 bv = *(const bf16x8*)(Bp + k0);
#pragma unroll
    for (int rt = 0; rt < 4; rt++) {
      bf16x8 av = *(const bf16x8*)(as + (rt * 16 + r) * 264 + quad * 8 + k0);
      acc1[rt] = __builtin_amdgcn_mfma_f32_16x16x32_bf16(av, bv, acc1[rt], 0, 0, 0);
    }
  }
  __syncthreads();  // REQUIRED: all as reads done before h aliases over it
  // h (bias + relu + bf16) -> LDS (aliased into as, stride 132)
  {
    int col = w * 16 + r;
    float bias = b1[col];
#pragma unroll
    for (int rt = 0; rt < 4; rt++)
#pragma unroll
      for (int reg = 0; reg < 4; reg++)
        hs[(rt * 16 + quad * 4 + reg) * 132 + col] =
            f2bf(fmaxf(acc1[rt][reg] + bias, 0.f));
  }
  __syncthreads();

  // ---- phase 2: [p|q] = h @ Wt2 ----
  int rt2 = w >> 1, ng = w & 1;
  int nbeg = ng ? 3 : 0;
  int ncnt = ng ? 2 : 3;
  const unsigned short* hrow = hs + (rt2 * 16 + r) * 132 + quad * 8;
  const unsigned short* Bp2 = Wt2 + (size_t)(nbeg * 16 + r) * 128 + quad * 8;
  f32x4 acc2[3];
#pragma unroll
  for (int j = 0; j < 3; j++) acc2[j] = (f32x4){0.f, 0.f, 0.f, 0.f};
#pragma unroll
  for (int k0 = 0; k0 < 128; k0 += 32) {
    ushort4 h0 = *(const ushort4*)(hrow + k0);       // 8B-aligned ds_read_b64
    ushort4 h1 = *(const ushort4*)(hrow + k0 + 4);
    bf16x8 af;
    af[0] = (short)h0.x; af[1] = (short)h0.y; af[2] = (short)h0.z; af[3] = (short)h0.w;
    af[4] = (short)h1.x; af[5] = (short)h1.y; af[6] = (short)h1.z; af[7] = (short)h1.w;
#pragma unroll
    for (int j = 0; j < 3; j++) {
      if (j < ncnt) {
        bf16x8 bv = *(const bf16x8*)(Bp2 + (size_t)j * 16 * 128 + k0);
        acc2[j] = __builtin_amdgcn_mfma_f32_16x16x32_bf16(af, bv, acc2[j], 0, 0, 0);
      }
    }
  }
  int crow0 = row0 + rt2 * 16 + quad * 4;
#pragma unroll
  for (int j = 0; j < 3; j++) {
    if (j < ncnt) {
      int col = (nbeg + j) * 16 + r;
#pragma unroll
      for (int reg = 0; reg < 4; reg++) {
        int row = crow0 + reg;
        if (row < N_NODES) {
          float v = acc2[j][reg];
          if (col < N_CLASSES)
            pb[(size_t)row * 40 + col] = f2bf(v);
          else
            q[(size_t)row * N_CLASSES + (col - N_CLASSES)] = v + b2[col - N_CLASSES];
        }
      }
    }
  }
}

// ---------------------------------------------------------------------------
// Fused: layer-2 gather-mean (bf16 p, stride 40) + root + ReLU + log_softmax.
// Wave per node, 8 edge-slots (unrolled x2) x (5 active lanes x 16B).
__global__ __launch_bounds__(256) void k_final(
    const unsigned short* __restrict__ pb, const float* __restrict__ q,
    const int* __restrict__ rs, const int* __restrict__ srcs,
    const float* __restrict__ invdeg, float* __restrict__ out) {
  int node = blockIdx.x * 4 + (threadIdx.x >> 6);
  int lane = threadIdx.x & 63;
  int slot = lane >> 3, li = lane & 7;
  if (node >= N_NODES) return;
  bool valid = li < 5;  // lane li covers cols li*8..li*8+7 (<40)
  int beg = rs[node], end = rs[node + 1];
  float acc[8];
#pragma unroll
  for (int j = 0; j < 8; j++) acc[j] = 0.f;
  int i = beg + slot;
  for (; i + 8 < end; i += 16) {
    int s0 = srcs[i], s1 = srcs[i + 8];
    if (valid) {
      u16x8 v0 = *(const u16x8*)(pb + (size_t)s0 * 40 + li * 8);
      u16x8 v1 = *(const u16x8*)(pb + (size_t)s1 * 40 + li * 8);
#pragma unroll
      for (int j = 0; j < 8; j++) acc[j] += bf2f(v0[j]) + bf2f(v1[j]);
    }
  }
  if (i < end) {
    int s0 = srcs[i];
    if (valid) {
      u16x8 v0 = *(const u16x8*)(pb + (size_t)s0 * 40 + li * 8);
#pragma unroll
      for (int j = 0; j < 8; j++) acc[j] += bf2f(v0[j]);
    }
  }
#pragma unroll
  for (int off = 8; off <= 32; off <<= 1)
#pragma unroll
    for (int j = 0; j < 8; j++) acc[j] += __shfl_xor(acc[j], off, 64);
  float inv = invdeg[node];
  float v[8];
  float m = -1e30f;
  if (valid) {
    const float* qr = q + (size_t)node * N_CLASSES + li * 8;
    float4 q0 = *(const float4*)qr;
    float4 q1 = *(const float4*)(qr + 4);
    v[0] = fmaxf(acc[0] * inv + q0.x, 0.f);
    v[1] = fmaxf(acc[1] * inv + q0.y, 0.f);
    v[2] = fmaxf(acc[2] * inv + q0.z, 0.f);
    v[3] = fmaxf(acc[3] * inv + q0.w, 0.f);
    v[4] = fmaxf(acc[4] * inv + q1.x, 0.f);
    v[5] = fmaxf(acc[5] * inv + q1.y, 0.f);
    v[6] = fmaxf(acc[6] * inv + q1.z, 0.f);
    v[7] = fmaxf(acc[7] * inv + q1.w, 0.f);
#pragma unroll
    for (int j = 0; j < 8; j++) m = fmaxf(m, v[j]);
  }
#pragma unroll
  for (int off = 1; off <= 4; off <<= 1) m = fmaxf(m, __shfl_xor(m, off, 8));
  float ssum = 0.f;
  if (valid) {
#pragma unroll
    for (int j = 0; j < 8; j++) ssum += __expf(v[j] - m);
  }
#pragma unroll
  for (int off = 1; off <= 4; off <<= 1) ssum += __shfl_xor(ssum, off, 8);
  float lse = __logf(ssum) + m;
  if (slot == 0 && valid) {
    float* orow = out + (size_t)node * N_CLASSES + li * 8;
    *(float4*)orow = make_float4(v[0] - lse, v[1] - lse, v[2] - lse, v[3] - lse);
    *(float4*)(orow + 4) =
        make_float4(v[4] - lse, v[5] - lse, v[6] - lse, v[7] - lse);
  }
}

// ---------------------------------------------------------------------------
extern "C" void kernel_launch(void* const* d_in, const int* in_sizes, int n_in,
                              void* d_out, int out_size, void* d_ws,
                              size_t ws_size, hipStream_t stream) {
  const float* x   = (const float*)d_in[0];
  const int*   ei  = (const int*)d_in[1];
  const int*   src = ei;
  const int*   dst = ei + N_EDGES;
  const float* W1l = (const float*)d_in[2];
  const float* W1r = (const float*)d_in[3];
  const float* b1  = (const float*)d_in[4];
  const float* W2l = (const float*)d_in[5];
  const float* W2r = (const float*)d_in[6];
  const float* b2  = (const float*)d_in[7];
  float* out = (float*)d_out;

  float* wsf = (float*)d_ws;
  int*   rs     = (int*)wsf + OFF_RS;
  int*   bcnt   = (int*)wsf + OFF_BCNT;
  float* invdeg = wsf + OFF_INVDEG;
  int*   srcs   = (int*)wsf + OFF_SRCS;
  unsigned short* xb  = (unsigned short*)(wsf + OFF_XB);
  unsigned short* pb  = (unsigned short*)(wsf + OFF_PB);  // dead-bins region
  unsigned short* Wt1 = (unsigned short*)(wsf + OFF_WT1);
  unsigned short* Wt2 = (unsigned short*)(wsf + OFF_WT2);
  int*   bins   = (int*)wsf + OFF_BINS;
  float* q = wsf + OFF_Q;  // dead-bins region

  hipMemsetAsync(bcnt, 0, NBUCKET * sizeof(int), stream);

  k_binA_prep<<<BINA_NBLK + PREP_NBLK, 256, 0, stream>>>(
      src, dst, bcnt, bins, x, W1l, W1r, W2l, W2r, xb, Wt1, Wt2);
  k_binB<<<NBUCKET, 256, 0, stream>>>(bcnt, bins, rs, srcs, invdeg);
  k_fused<<<(N_NODES + 63) / 64, 512, 0, stream>>>(
      xb, rs, srcs, invdeg, Wt1, Wt2, b1, b2, pb, q);
  k_final<<<(N_NODES + 3) / 4, 256, 0, stream>>>(pb, q, rs, srcs, invdeg, out);
}